// Round 5
// baseline (67.951 us; speedup 1.0000x reference)
//
#include <hip/hip_runtime.h>
#include <hip/hip_bf16.h>

#define D 256
#define NROWS 8192
#define LBATCH 4096
#define LX 4160          // 4096 + 64 virtual prefix
#define VPAD 64

#define QBLK 32          // attn rows per block
#define KKEYS 96         // staged keys per block (3 x 32 MFMA k-steps)
#define VSTR 104         // VtS row stride (u16)
#define SSTR 100         // Sb row stride (f32)
#define PSTR 104         // Pb row stride (u16)
#define MSTR 264         // Mlds row stride (u16): 132 dw -> 2-way max
#define WS_N 68          // Ws row stride (u16)

typedef unsigned int u32;
typedef unsigned short u16;

typedef short bf16x8 __attribute__((ext_vector_type(8)));
typedef float f32x4 __attribute__((ext_vector_type(4)));

__device__ __forceinline__ u16 f2bf(float f) {
    u32 x = __float_as_uint(f);
    x += 0x7fffu + ((x >> 16) & 1u);
    return (u16)(x >> 16);
}
__device__ __forceinline__ u32 pk2(float a, float b) {
    return (u32)f2bf(a) | ((u32)f2bf(b) << 16);
}

// ---------------- Kernel 0: prep (weight transpose + virtual prefixes) ----------------
__global__ __launch_bounds__(256) void prep(
    const float* __restrict__ Wq, const float* __restrict__ Wk,
    const float* __restrict__ Wv, const float* __restrict__ Wo,
    const float* __restrict__ bk, const float* __restrict__ bv,
    u16* __restrict__ Wt, u16* __restrict__ Kx, u16* __restrict__ Vt)
{
    const int b = blockIdx.x, t = threadIdx.x;
    if (b < 64) {
        __shared__ float T[64][69];
        const int m = b >> 4, tile = b & 15;
        const int k0 = (tile >> 2) * 64, o0 = (tile & 3) * 64;
        const float* __restrict__ W = (m == 0) ? Wq : (m == 1) ? Wk : (m == 2) ? Wv : Wo;
        const int r = t >> 2, c0 = (t & 3) * 16;
        #pragma unroll
        for (int j = 0; j < 4; ++j) {
            float4 v = *(const float4*)&W[(k0 + r) * 256 + o0 + c0 + j * 4];
            T[r][c0 + j * 4 + 0] = v.x; T[r][c0 + j * 4 + 1] = v.y;
            T[r][c0 + j * 4 + 2] = v.z; T[r][c0 + j * 4 + 3] = v.w;
        }
        __syncthreads();
        const int orow = t >> 2, ck0 = (t & 3) * 16;
        float tv[16];
        #pragma unroll
        for (int j = 0; j < 16; ++j) tv[j] = T[ck0 + j][orow];
        u32 pw[8];
        #pragma unroll
        for (int j = 0; j < 8; ++j) pw[j] = pk2(tv[2 * j], tv[2 * j + 1]);
        uint4* dst = (uint4*)&Wt[(size_t)(m * 256 + o0 + orow) * 256 + k0 + ck0];
        dst[0] = *(uint4*)&pw[0];
        dst[1] = *(uint4*)&pw[4];
    } else if (b < 80) {
        const int g = (b - 64) * 256 + t;          // 0..4095
        const int batch = g >> 11, rem = g & 2047;
        const int r = rem >> 5, c8 = rem & 31;
        float4 f0 = *(const float4*)&bk[c8 * 8];
        float4 f1 = *(const float4*)&bk[c8 * 8 + 4];
        uint4 o;
        o.x = pk2(f0.x, f0.y); o.y = pk2(f0.z, f0.w);
        o.z = pk2(f1.x, f1.y); o.w = pk2(f1.z, f1.w);
        *(uint4*)&Kx[((size_t)batch * LX + r) * 256 + c8 * 8] = o;
    } else {
        const int g = (b - 80) * 256 + t;          // 0..4095
        const int batch = g >> 11, rem = g & 2047;
        const int d = rem >> 3, seg = rem & 7;
        const u16 val = f2bf(bv[d]);
        const u32 vv = (u32)val | ((u32)val << 16);
        uint4 o; o.x = vv; o.y = vv; o.z = vv; o.w = vv;
        *(uint4*)&Vt[((size_t)batch * 256 + d) * LX + seg * 8] = o;
    }
}

// ---------------- Kernel 1: QKV projection (MFMA, LDS-staged A and B) ----------------
// 64 rows x 128 cols per block over [8192 x 768]
__global__ __launch_bounds__(256) void qkv_mfma(
    const float* __restrict__ H, const u16* __restrict__ Wt,
    const float* __restrict__ bq, const float* __restrict__ bkb,
    const float* __restrict__ bvb,
    u16* __restrict__ Qb, u16* __restrict__ Kx, u16* __restrict__ Vt)
{
    __shared__ u16 As[64 * 256];
    __shared__ u16 Bs[2][128 * 68];

    const int tid = threadIdx.x;
    const int bx = blockIdx.x;     // 0..5
    const int by = blockIdx.y;     // 0..127
    const int row0 = by * 64;
    const u16* __restrict__ wb = Wt + (size_t)(bx * 128) * 256;

    uint4 breg[4];
    #pragma unroll
    for (int i = 0; i < 4; ++i) {
        const int u = i * 256 + tid, col = u >> 3, seg = u & 7;
        breg[i] = *(const uint4*)&wb[col * 256 + seg * 8];
    }
    {
        const int r = tid >> 2, cb = (tid & 3) * 64;
        const float* hp = H + (size_t)(row0 + r) * 256 + cb;
        const int swz = (r & 7) << 3;
        #pragma unroll
        for (int i = 0; i < 16; ++i) {
            float4 h4 = *(const float4*)(hp + i * 4);
            uint2 pv; pv.x = pk2(h4.x, h4.y); pv.y = pk2(h4.z, h4.w);
            *(uint2*)(As + ((r * 256 + cb + i * 4) ^ swz)) = pv;
        }
    }
    #pragma unroll
    for (int i = 0; i < 4; ++i) {
        const int u = i * 256 + tid, col = u >> 3, seg = u & 7;
        *(uint4*)&Bs[0][col * 68 + seg * 8] = breg[i];
    }
    __syncthreads();

    const int lane = tid & 63, w = tid >> 6;
    const int l15 = lane & 15, lhi = lane >> 4;
    const int rowa = w * 16 + l15;
    const int kb = lhi * 8;
    const int swa = (rowa & 7) << 3;

    bf16x8 af[8];
    #pragma unroll
    for (int ks = 0; ks < 8; ++ks)
        af[ks] = *(const bf16x8*)(As + ((rowa * 256 + ks * 32 + kb) ^ swa));

    f32x4 acc[8];
    #pragma unroll
    for (int i = 0; i < 8; ++i) acc[i] = (f32x4){0.f, 0.f, 0.f, 0.f};

    for (int s = 0; s < 4; ++s) {
        if (s < 3) {
            #pragma unroll
            for (int i = 0; i < 4; ++i) {
                const int u = i * 256 + tid, col = u >> 3, seg = u & 7;
                breg[i] = *(const uint4*)&wb[col * 256 + (s + 1) * 64 + seg * 8];
            }
        }
        #pragma unroll
        for (int ks2 = 0; ks2 < 2; ++ks2) {
            const int ks = s * 2 + ks2;
            #pragma unroll
            for (int i = 0; i < 8; ++i) {
                bf16x8 bf = *(const bf16x8*)&Bs[s & 1][(i * 16 + l15) * 68 + ks2 * 32 + kb];
                acc[i] = __builtin_amdgcn_mfma_f32_16x16x32_bf16(af[ks], bf, acc[i], 0, 0, 0);
            }
        }
        if (s < 3) {
            __syncthreads();
            #pragma unroll
            for (int i = 0; i < 4; ++i) {
                const int u = i * 256 + tid, col = u >> 3, seg = u & 7;
                *(uint4*)&Bs[(s + 1) & 1][col * 68 + seg * 8] = breg[i];
            }
            __syncthreads();
        }
    }

    const int mat = bx >> 1;   // 0=Q 1=K 2=V
    const int batch = row0 >> 12, lr0 = row0 & 4095;

    if (mat == 2) {
        // V: bounce through LDS (reuse As) to produce coalesced transposed stores.
        u16* Vtmp = As;   // [128][72]
        #pragma unroll
        for (int i = 0; i < 8; ++i) {
            const int dl = i * 16 + l15;               // local dim 0..127
            const float bi = bvb[(bx & 1) * 128 + dl];
            #pragma unroll
            for (int reg = 0; reg < 4; ++reg) {
                const int key = w * 16 + lhi * 4 + reg;  // local key 0..63
                Vtmp[dl * 72 + key] = f2bf(acc[i][reg] + bi);
            }
        }
        __syncthreads();
        #pragma unroll
        for (int rep = 0; rep < 2; ++rep) {
            const int dl = rep * 64 + (tid >> 2), q = tid & 3;
            uint4 v0 = *(const uint4*)&Vtmp[dl * 72 + q * 16];
            uint4 v1 = *(const uint4*)&Vtmp[dl * 72 + q * 16 + 8];
            const int gd = (bx & 1) * 128 + dl;
            u16* dst = Vt + ((size_t)batch * 256 + gd) * LX + VPAD + lr0 + q * 16;
            *(uint4*)dst = v0;
            *(uint4*)(dst + 8) = v1;
        }
    } else {
        const float* bias = (mat == 0) ? bq : bkb;
        const int rbase = row0 + w * 16 + lhi * 4;
        #pragma unroll
        for (int i = 0; i < 8; ++i) {
            const int colm = (bx * 128 + i * 16 + l15) & 255;
            const float bi = bias[colm];
            #pragma unroll
            for (int reg = 0; reg < 4; ++reg) {
                const int r = rbase + reg;
                const u16 v = f2bf(acc[i][reg] + bi);
                if (mat == 0) Qb[(size_t)r * 256 + colm] = v;
                else Kx[((size_t)(r >> 12) * LX + VPAD + (r & 4095)) * 256 + colm] = v;
            }
        }
    }
}

// ---------------- Kernel 2: fused attention + output projection + residual ----------------
// 32 rows/block, 512 threads. Phases: stage K/V -> QK^T -> softmax (+Wo slice0 stage)
// -> PV (M to LDS) -> out-GEMM (4 k-slices) -> out = H + M@WoT + bo.
__global__ __launch_bounds__(512) void attn_out(
    const u16* __restrict__ Qb, const u16* __restrict__ Kx,
    const u16* __restrict__ Vt, const u16* __restrict__ Wt,
    const float* __restrict__ bo, const float* __restrict__ H,
    float* __restrict__ out)
{
    __shared__ __align__(16) char smem[121856];
    u16*  Ks   = (u16*)smem;                  // [96][256] swizzled   (dead after QK^T)
    float* Sb  = (float*)(smem + 49152);      // [32][SSTR]           (dead after softmax)
    u16*  Pb   = (u16*)(smem + 61952);        // [32][PSTR]           (live till PV)
    u16*  VtS  = (u16*)(smem + 68608);        // [256][VSTR]          (live till PV)
    u16*  Ws   = (u16*)smem;                  // [256][WS_N] overlays Ks (phase 5)
    u16*  Mlds = (u16*)(smem + 34816);        // [32][MSTR] overlays Ks tail + Sb

    const int tid = threadIdx.x;
    const int lane = tid & 63, w = tid >> 6;
    const int l15 = lane & 15, lhi = lane >> 4;
    const int r0 = blockIdx.x * QBLK;
    const int batch = r0 >> 12;
    const int lb0 = r0 & 4095;
    const size_t kbase = (size_t)batch * LX + lb0;
    const u16* __restrict__ wo = Wt + (size_t)768 * 256;

    // ---- stage K (swizzled) and V^T (coalesced) ----
    uint4 kreg[6], vreg[6];
    #pragma unroll
    for (int i = 0; i < 6; ++i) {
        const int u = i * 512 + tid;
        const int row = u >> 5, seg = u & 31;
        kreg[i] = *(const uint4*)&Kx[(kbase + row) * 256 + seg * 8];
    }
    #pragma unroll
    for (int i = 0; i < 6; ++i) {
        const int u = i * 512 + tid;
        const int d = (u * 21846) >> 18;       // u/12
        const int seg = u - d * 12;
        vreg[i] = *(const uint4*)&Vt[((size_t)batch * 256 + d) * LX + lb0 + seg * 8];
    }
    #pragma unroll
    for (int i = 0; i < 6; ++i) {
        const int u = i * 512 + tid;
        const int row = u >> 5, seg = u & 31;
        *(uint4*)&Ks[row * 256 + (seg ^ (row & 7)) * 8] = kreg[i];
    }
    #pragma unroll
    for (int i = 0; i < 6; ++i) {
        const int u = i * 512 + tid;
        const int d = (u * 21846) >> 18;
        const int seg = u - d * 12;
        *(uint4*)&VtS[d * VSTR + seg * 8] = vreg[i];
    }
    __syncthreads();

    // ---- QK^T: 12 C-tiles (2 rowtiles x 6 keytiles) over 8 waves ----
    const float scale = 0.0625f;
    #pragma unroll
    for (int pass = 0; pass < 2; ++pass) {
        const int T = (pass == 0) ? w : w + 8;
        if (pass == 1 && w >= 4) break;
        const int rt = (T >= 6) ? 1 : 0;
        const int kt = T - rt * 6;
        const u16* qp = Qb + (size_t)(r0 + rt * 16 + l15) * 256;
        const int key = kt * 16 + l15;
        f32x4 acc = (f32x4){0.f, 0.f, 0.f, 0.f};
        #pragma unroll
        for (int ks = 0; ks < 8; ++ks) {
            bf16x8 qf = *(const bf16x8*)(qp + ks * 32 + lhi * 8);
            bf16x8 kf = *(const bf16x8*)&Ks[key * 256 + ((ks * 4 + lhi) ^ (key & 7)) * 8];
            acc = __builtin_amdgcn_mfma_f32_16x16x32_bf16(qf, kf, acc, 0, 0, 0);
        }
        #pragma unroll
        for (int reg = 0; reg < 4; ++reg)
            Sb[(rt * 16 + lhi * 4 + reg) * SSTR + kt * 16 + l15] = acc[reg] * scale;
    }
    __syncthreads();

    // ---- softmax (+ issue Wo slice-0 staging loads for overlap) ----
    uint4 wr[4];
    #pragma unroll
    for (int i2 = 0; i2 < 4; ++i2) {
        const int u = i2 * 512 + tid, n = u >> 3, seg = u & 7;
        wr[i2] = *(const uint4*)&wo[n * 256 + seg * 8];
    }
    {
        const int ri = w * 4 + lhi;
        const int jb = l15;
        float s6[6];
        float m = -1e30f;
        #pragma unroll
        for (int c = 0; c < 6; ++c) {
            const int j = jb + 16 * c;
            const float x = Sb[ri * SSTR + j];
            const bool v = (j >= ri + 1) && (j <= ri + 64);
            s6[c] = v ? x : -1e30f;
            m = fmaxf(m, s6[c]);
        }
        #pragma unroll
        for (int o = 1; o < 16; o <<= 1) m = fmaxf(m, __shfl_xor(m, o));
        float e6[6], z64 = 0.f, z16 = 0.f, z4 = 0.f;
        #pragma unroll
        for (int c = 0; c < 6; ++c) {
            const int j = jb + 16 * c;
            const float e = __expf(s6[c] - m);
            e6[c] = e;
            z64 += e;
            if (j >= ri + 49) z16 += e;
            if (j >= ri + 61) z4 += e;
        }
        #pragma unroll
        for (int o = 1; o < 16; o <<= 1) {
            z64 += __shfl_xor(z64, o);
            z16 += __shfl_xor(z16, o);
            z4  += __shfl_xor(z4, o);
        }
        const float i64 = 1.f / z64, i16 = 1.f / z16, i4 = 1.f / z4;
        #pragma unroll
        for (int c = 0; c < 6; ++c) {
            const int j = jb + 16 * c;
            float wt = e6[c] * (i64 + (j >= ri + 49 ? i16 : 0.f) + (j >= ri + 61 ? i4 : 0.f)) * (1.f / 3.f);
            Pb[ri * PSTR + j] = f2bf(wt);
        }
    }
    // write Wo slice 0 into Ws (overlays dead Ks)
    #pragma unroll
    for (int i2 = 0; i2 < 4; ++i2) {
        const int u = i2 * 512 + tid, n = u >> 3, seg = u & 7;
        *(uint4*)&Ws[n * WS_N + seg * 8] = wr[i2];
    }
    __syncthreads();

    // ---- PV: M[32][256] = P[32][96] @ V[96][256] -> Mlds ----
    #pragma unroll
    for (int rt = 0; rt < 2; ++rt) {
        bf16x8 pa[3];
        #pragma unroll
        for (int ks = 0; ks < 3; ++ks)
            pa[ks] = *(const bf16x8*)&Pb[(rt * 16 + l15) * PSTR + ks * 32 + lhi * 8];
        #pragma unroll
        for (int dd = 0; dd < 2; ++dd) {
            const int dt = w * 2 + dd;
            f32x4 acc = (f32x4){0.f, 0.f, 0.f, 0.f};
            #pragma unroll
            for (int ks = 0; ks < 3; ++ks) {
                bf16x8 vb = *(const bf16x8*)&VtS[(dt * 16 + l15) * VSTR + ks * 32 + lhi * 8];
                acc = __builtin_amdgcn_mfma_f32_16x16x32_bf16(pa[ks], vb, acc, 0, 0, 0);
            }
            #pragma unroll
            for (int reg = 0; reg < 4; ++reg)
                Mlds[(rt * 16 + lhi * 4 + reg) * MSTR + dt * 16 + l15] = f2bf(acc[reg]);
        }
    }
    __syncthreads();

    // ---- out-GEMM: out[32][256] = H + M @ WoT + bo; 4 k-slices, Ws single-buffered ----
    bf16x8 afm[2][8];
    #pragma unroll
    for (int rt = 0; rt < 2; ++rt)
        #pragma unroll
        for (int ks = 0; ks < 8; ++ks)
            afm[rt][ks] = *(const bf16x8*)&Mlds[(rt * 16 + l15) * MSTR + ks * 32 + lhi * 8];

    f32x4 oac[2][2];
    #pragma unroll
    for (int rt = 0; rt < 2; ++rt)
        #pragma unroll
        for (int dd = 0; dd < 2; ++dd)
            oac[rt][dd] = (f32x4){0.f, 0.f, 0.f, 0.f};

    for (int s = 0; s < 4; ++s) {
        if (s < 3) {
            #pragma unroll
            for (int i2 = 0; i2 < 4; ++i2) {
                const int u = i2 * 512 + tid, n = u >> 3, seg = u & 7;
                wr[i2] = *(const uint4*)&wo[n * 256 + (s + 1) * 64 + seg * 8];
            }
        }
        #pragma unroll
        for (int ks2 = 0; ks2 < 2; ++ks2) {
            #pragma unroll
            for (int dd = 0; dd < 2; ++dd) {
                bf16x8 bf = *(const bf16x8*)&Ws[((w * 2 + dd) * 16 + l15) * WS_N + ks2 * 32 + lhi * 8];
                #pragma unroll
                for (int rt = 0; rt < 2; ++rt)
                    oac[rt][dd] = __builtin_amdgcn_mfma_f32_16x16x32_bf16(afm[rt][s * 2 + ks2], bf, oac[rt][dd], 0, 0, 0);
            }
        }
        if (s < 3) {
            __syncthreads();
            #pragma unroll
            for (int i2 = 0; i2 < 4; ++i2) {
                const int u = i2 * 512 + tid, n = u >> 3, seg = u & 7;
                *(uint4*)&Ws[n * WS_N + seg * 8] = wr[i2];
            }
            __syncthreads();
        }
    }

    #pragma unroll
    for (int rt = 0; rt < 2; ++rt)
        #pragma unroll
        for (int dd = 0; dd < 2; ++dd) {
            const int col = (w * 2 + dd) * 16 + l15;
            const float bi = bo[col];
            #pragma unroll
            for (int reg = 0; reg < 4; ++reg) {
                const int r = r0 + rt * 16 + lhi * 4 + reg;
                const size_t off = (size_t)r * 256 + col;
                out[off] = H[off] + oac[rt][dd][reg] + bi;
            }
        }
}

extern "C" void kernel_launch(void* const* d_in, const int* in_sizes, int n_in,
                              void* d_out, int out_size, void* d_ws, size_t ws_size,
                              hipStream_t stream) {
    const float* H  = (const float*)d_in[0];
    const float* Wq = (const float*)d_in[1];
    const float* bq = (const float*)d_in[2];
    const float* Wk = (const float*)d_in[3];
    const float* bk = (const float*)d_in[4];
    const float* Wv = (const float*)d_in[5];
    const float* bv = (const float*)d_in[6];
    const float* Wo = (const float*)d_in[7];
    const float* bo = (const float*)d_in[8];
    float* out = (float*)d_out;

    u16* Wt = (u16*)d_ws;                          // 1024*256
    u16* Qb = Wt + 1024 * 256;                     // 8192*256
    u16* Kx = Qb + (size_t)NROWS * 256;            // 2*4160*256
    u16* Vt = Kx + (size_t)2 * LX * 256;           // 2*256*4160

    prep<<<96, 256, 0, stream>>>(Wq, Wk, Wv, Wo, bk, bv, Wt, Kx, Vt);
    qkv_mfma<<<dim3(6, 128), 256, 0, stream>>>(H, Wt, bq, bk, bv, Qb, Kx, Vt);
    attn_out<<<256, 512, 0, stream>>>(Qb, Kx, Vt, Wt, bo, H, out);
}

// Round 6
// 58.444 us; speedup vs baseline: 1.1627x; 1.1627x over previous
//
#include <hip/hip_runtime.h>
#include <hip/hip_bf16.h>

#define D 256
#define NROWS 8192
#define LBATCH 4096
#define LXK 4160         // Kx row count per batch: 64 prefix + 4096
#define LXV 4176         // Vt col stride per batch: 64 prefix + 4096 + 16 tail pad
#define VPAD 64

#define QBLK 16          // attn rows per block
#define KKEYS 80         // staged keys per block
#define SSTR 84          // Sb row stride (f32)
#define PSTR 104         // Pb row stride (u16), cols 80..95 zeroed

typedef unsigned int u32;
typedef unsigned short u16;

typedef short bf16x8 __attribute__((ext_vector_type(8)));
typedef float f32x4 __attribute__((ext_vector_type(4)));

__device__ __forceinline__ u16 f2bf(float f) {
    u32 x = __float_as_uint(f);
    x += 0x7fffu + ((x >> 16) & 1u);
    return (u16)(x >> 16);
}
__device__ __forceinline__ u32 pk2(float a, float b) {
    return (u32)f2bf(a) | ((u32)f2bf(b) << 16);
}

// ---------------- Kernel 0: prep (weight transpose + virtual prefixes) ----------------
__global__ __launch_bounds__(256) void prep(
    const float* __restrict__ Wq, const float* __restrict__ Wk,
    const float* __restrict__ Wv, const float* __restrict__ Wo,
    const float* __restrict__ bk, const float* __restrict__ bv,
    u16* __restrict__ Wt, u16* __restrict__ Kx, u16* __restrict__ Vt)
{
    const int b = blockIdx.x, t = threadIdx.x;
    if (b < 64) {
        __shared__ float T[64][69];
        const int m = b >> 4, tile = b & 15;
        const int k0 = (tile >> 2) * 64, o0 = (tile & 3) * 64;
        const float* __restrict__ W = (m == 0) ? Wq : (m == 1) ? Wk : (m == 2) ? Wv : Wo;
        const int r = t >> 2, c0 = (t & 3) * 16;
        #pragma unroll
        for (int j = 0; j < 4; ++j) {
            float4 v = *(const float4*)&W[(k0 + r) * 256 + o0 + c0 + j * 4];
            T[r][c0 + j * 4 + 0] = v.x; T[r][c0 + j * 4 + 1] = v.y;
            T[r][c0 + j * 4 + 2] = v.z; T[r][c0 + j * 4 + 3] = v.w;
        }
        __syncthreads();
        const int orow = t >> 2, ck0 = (t & 3) * 16;
        float tv[16];
        #pragma unroll
        for (int j = 0; j < 16; ++j) tv[j] = T[ck0 + j][orow];
        u32 pw[8];
        #pragma unroll
        for (int j = 0; j < 8; ++j) pw[j] = pk2(tv[2 * j], tv[2 * j + 1]);
        uint4* dst = (uint4*)&Wt[(size_t)(m * 256 + o0 + orow) * 256 + k0 + ck0];
        dst[0] = *(uint4*)&pw[0];
        dst[1] = *(uint4*)&pw[4];
    } else if (b < 80) {
        const int g = (b - 64) * 256 + t;          // 0..4095
        const int batch = g >> 11, rem = g & 2047;
        const int r = rem >> 5, c8 = rem & 31;
        float4 f0 = *(const float4*)&bk[c8 * 8];
        float4 f1 = *(const float4*)&bk[c8 * 8 + 4];
        uint4 o;
        o.x = pk2(f0.x, f0.y); o.y = pk2(f0.z, f0.w);
        o.z = pk2(f1.x, f1.y); o.w = pk2(f1.z, f1.w);
        *(uint4*)&Kx[((size_t)batch * LXK + r) * 256 + c8 * 8] = o;
    } else {
        const int g = (b - 80) * 256 + t;          // 0..4095
        const int batch = g >> 11, rem = g & 2047;
        const int d = rem >> 3, seg = rem & 7;
        const u16 val = f2bf(bv[d]);
        const u32 vv = (u32)val | ((u32)val << 16);
        uint4 o; o.x = vv; o.y = vv; o.z = vv; o.w = vv;
        *(uint4*)&Vt[((size_t)batch * 256 + d) * LXV + seg * 8] = o;
    }
}

// ---------------- Kernel 1: QKV projection (MFMA, LDS-staged A and B) ----------------
__global__ __launch_bounds__(256) void qkv_mfma(
    const float* __restrict__ H, const u16* __restrict__ Wt,
    const float* __restrict__ bq, const float* __restrict__ bkb,
    const float* __restrict__ bvb,
    u16* __restrict__ Qb, u16* __restrict__ Kx, u16* __restrict__ Vt)
{
    __shared__ u16 As[64 * 256];
    __shared__ u16 Bs[2][128 * 68];

    const int tid = threadIdx.x;
    const int bx = blockIdx.x;     // 0..5
    const int by = blockIdx.y;     // 0..127
    const int row0 = by * 64;
    const u16* __restrict__ wb = Wt + (size_t)(bx * 128) * 256;

    uint4 breg[4];
    #pragma unroll
    for (int i = 0; i < 4; ++i) {
        const int u = i * 256 + tid, col = u >> 3, seg = u & 7;
        breg[i] = *(const uint4*)&wb[col * 256 + seg * 8];
    }
    {
        const int r = tid >> 2, cb = (tid & 3) * 64;
        const float* hp = H + (size_t)(row0 + r) * 256 + cb;
        const int swz = (r & 7) << 3;
        #pragma unroll
        for (int i = 0; i < 16; ++i) {
            float4 h4 = *(const float4*)(hp + i * 4);
            uint2 pv; pv.x = pk2(h4.x, h4.y); pv.y = pk2(h4.z, h4.w);
            *(uint2*)(As + ((r * 256 + cb + i * 4) ^ swz)) = pv;
        }
    }
    #pragma unroll
    for (int i = 0; i < 4; ++i) {
        const int u = i * 256 + tid, col = u >> 3, seg = u & 7;
        *(uint4*)&Bs[0][col * 68 + seg * 8] = breg[i];
    }
    __syncthreads();

    const int lane = tid & 63, w = tid >> 6;
    const int l15 = lane & 15, lhi = lane >> 4;
    const int rowa = w * 16 + l15;
    const int kb = lhi * 8;
    const int swa = (rowa & 7) << 3;

    bf16x8 af[8];
    #pragma unroll
    for (int ks = 0; ks < 8; ++ks)
        af[ks] = *(const bf16x8*)(As + ((rowa * 256 + ks * 32 + kb) ^ swa));

    f32x4 acc[8];
    #pragma unroll
    for (int i = 0; i < 8; ++i) acc[i] = (f32x4){0.f, 0.f, 0.f, 0.f};

    for (int s = 0; s < 4; ++s) {
        if (s < 3) {
            #pragma unroll
            for (int i = 0; i < 4; ++i) {
                const int u = i * 256 + tid, col = u >> 3, seg = u & 7;
                breg[i] = *(const uint4*)&wb[col * 256 + (s + 1) * 64 + seg * 8];
            }
        }
        #pragma unroll
        for (int ks2 = 0; ks2 < 2; ++ks2) {
            const int ks = s * 2 + ks2;
            #pragma unroll
            for (int i = 0; i < 8; ++i) {
                bf16x8 bf = *(const bf16x8*)&Bs[s & 1][(i * 16 + l15) * 68 + ks2 * 32 + kb];
                acc[i] = __builtin_amdgcn_mfma_f32_16x16x32_bf16(af[ks], bf, acc[i], 0, 0, 0);
            }
        }
        if (s < 3) {
            __syncthreads();
            #pragma unroll
            for (int i = 0; i < 4; ++i) {
                const int u = i * 256 + tid, col = u >> 3, seg = u & 7;
                *(uint4*)&Bs[(s + 1) & 1][col * 68 + seg * 8] = breg[i];
            }
            __syncthreads();
        }
    }

    const int mat = bx >> 1;   // 0=Q 1=K 2=V
    const int batch = row0 >> 12, lr0 = row0 & 4095;

    if (mat == 2) {
        // V: bounce through LDS (reuse As) for coalesced transposed stores.
        u16* Vtmp = As;   // [128][72]
        #pragma unroll
        for (int i = 0; i < 8; ++i) {
            const int dl = i * 16 + l15;               // local dim 0..127
            const float bi = bvb[(bx & 1) * 128 + dl];
            #pragma unroll
            for (int reg = 0; reg < 4; ++reg) {
                const int key = w * 16 + lhi * 4 + reg;  // local key 0..63
                Vtmp[dl * 72 + key] = f2bf(acc[i][reg] + bi);
            }
        }
        __syncthreads();
        #pragma unroll
        for (int rep = 0; rep < 2; ++rep) {
            const int dl = rep * 64 + (tid >> 2), q = tid & 3;
            uint4 v0 = *(const uint4*)&Vtmp[dl * 72 + q * 16];
            uint4 v1 = *(const uint4*)&Vtmp[dl * 72 + q * 16 + 8];
            const int gd = (bx & 1) * 128 + dl;
            u16* dst = Vt + ((size_t)batch * 256 + gd) * LXV + VPAD + lr0 + q * 16;
            *(uint4*)dst = v0;
            *(uint4*)(dst + 8) = v1;
        }
    } else {
        const float* bias = (mat == 0) ? bq : bkb;
        const int rbase = row0 + w * 16 + lhi * 4;
        #pragma unroll
        for (int i = 0; i < 8; ++i) {
            const int colm = (bx * 128 + i * 16 + l15) & 255;
            const float bi = bias[colm];
            #pragma unroll
            for (int reg = 0; reg < 4; ++reg) {
                const int r = rbase + reg;
                const u16 v = f2bf(acc[i][reg] + bi);
                if (mat == 0) Qb[(size_t)r * 256 + colm] = v;
                else Kx[((size_t)(r >> 12) * LXK + VPAD + (r & 4095)) * 256 + colm] = v;
            }
        }
    }
}

// ---------------- Kernel 2: fused 3-window attention (MFMA) ----------------
// 16 rows/block, 256 threads, grid 512 (2 blocks/CU). K staged in LDS (swizzled);
// V^T read directly from global (L2). valid j for row ri: [ri+1, ri+64].
__global__ __launch_bounds__(256) void attn_mfma(
    const u16* __restrict__ Qb, const u16* __restrict__ Kx,
    const u16* __restrict__ Vt, u16* __restrict__ Mb)
{
    __shared__ u16 Ks[KKEYS * 256];       // XOR-swizzled [key][feat]
    __shared__ float Sb[QBLK * SSTR];
    __shared__ u16 Pb[QBLK * PSTR];

    const int tid = threadIdx.x;
    const int lane = tid & 63, w = tid >> 6;   // w 0..3
    const int l15 = lane & 15, lhi = lane >> 4;
    const int r0 = blockIdx.x * QBLK;
    const int batch = r0 >> 12;
    const int lb0 = r0 & 4095;
    const size_t kbase = (size_t)batch * LXK + lb0;

    // ---- stage K (80 rows, swizzled) ----
    uint4 kreg[10];
    #pragma unroll
    for (int i = 0; i < 10; ++i) {
        const int u = i * 256 + tid;
        const int row = u >> 5, seg = u & 31;
        kreg[i] = *(const uint4*)&Kx[(kbase + row) * 256 + seg * 8];
    }
    #pragma unroll
    for (int i = 0; i < 10; ++i) {
        const int u = i * 256 + tid;
        const int row = u >> 5, seg = u & 31;
        *(uint4*)&Ks[row * 256 + (seg ^ (row & 7)) * 8] = kreg[i];
    }
    __syncthreads();

    // ---- QK^T: 5 keytiles over 4 waves (wave 0 also does tile 4) ----
    const float scale = 0.0625f;
    const u16* qp = Qb + (size_t)(r0 + l15) * 256;
    for (int T = w; T < 5; T += 4) {
        const int key = T * 16 + l15;
        f32x4 acc = (f32x4){0.f, 0.f, 0.f, 0.f};
        #pragma unroll
        for (int ks = 0; ks < 8; ++ks) {
            bf16x8 qf = *(const bf16x8*)(qp + ks * 32 + lhi * 8);
            bf16x8 kf = *(const bf16x8*)&Ks[key * 256 + ((ks * 4 + lhi) ^ (key & 7)) * 8];
            acc = __builtin_amdgcn_mfma_f32_16x16x32_bf16(qf, kf, acc, 0, 0, 0);
        }
        #pragma unroll
        for (int reg = 0; reg < 4; ++reg)
            Sb[(lhi * 4 + reg) * SSTR + T * 16 + l15] = acc[reg] * scale;
    }
    __syncthreads();

    // ---- nested softmax: 16 rows x 16 lanes, 5 cols/lane ----
    {
        const int ri = w * 4 + lhi;
        const int jb = l15;
        float s5[5];
        float m = -1e30f;
        #pragma unroll
        for (int c = 0; c < 5; ++c) {
            const int j = jb + 16 * c;
            const float x = Sb[ri * SSTR + j];
            const bool v = (j >= ri + 1) && (j <= ri + 64);
            s5[c] = v ? x : -1e30f;
            m = fmaxf(m, s5[c]);
        }
        #pragma unroll
        for (int o = 1; o < 16; o <<= 1) m = fmaxf(m, __shfl_xor(m, o));
        float e5[5], z64 = 0.f, z16 = 0.f, z4 = 0.f;
        #pragma unroll
        for (int c = 0; c < 5; ++c) {
            const int j = jb + 16 * c;
            const float e = __expf(s5[c] - m);
            e5[c] = e;
            z64 += e;
            if (j >= ri + 49) z16 += e;
            if (j >= ri + 61) z4 += e;
        }
        #pragma unroll
        for (int o = 1; o < 16; o <<= 1) {
            z64 += __shfl_xor(z64, o);
            z16 += __shfl_xor(z16, o);
            z4  += __shfl_xor(z4, o);
        }
        const float i64 = 1.f / z64, i16 = 1.f / z16, i4 = 1.f / z4;
        #pragma unroll
        for (int c = 0; c < 5; ++c) {
            const int j = jb + 16 * c;
            float wt = e5[c] * (i64 + (j >= ri + 49 ? i16 : 0.f) + (j >= ri + 61 ? i4 : 0.f)) * (1.f / 3.f);
            Pb[ri * PSTR + j] = f2bf(wt);
        }
        Pb[ri * PSTR + 80 + jb] = 0;   // zero pad cols 80..95
    }
    __syncthreads();

    // ---- PV: M[16][256] = P[16][96] @ V^T[96][256]; V fragments from global ----
    bf16x8 pa[3];
    #pragma unroll
    for (int ks = 0; ks < 3; ++ks)
        pa[ks] = *(const bf16x8*)&Pb[l15 * PSTR + ks * 32 + lhi * 8];
    #pragma unroll
    for (int i = 0; i < 4; ++i) {
        const int dt = w * 4 + i;
        const u16* vrow = Vt + ((size_t)batch * 256 + dt * 16 + l15) * LXV + lb0;
        f32x4 acc = (f32x4){0.f, 0.f, 0.f, 0.f};
        #pragma unroll
        for (int ks = 0; ks < 3; ++ks) {
            bf16x8 vb = *(const bf16x8*)(vrow + ks * 32 + lhi * 8);
            acc = __builtin_amdgcn_mfma_f32_16x16x32_bf16(pa[ks], vb, acc, 0, 0, 0);
        }
        #pragma unroll
        for (int reg = 0; reg < 4; ++reg)
            Mb[(size_t)(r0 + lhi * 4 + reg) * 256 + dt * 16 + l15] = f2bf(acc[reg]);
    }
}

// ---------------- Kernel 3: output projection + residual (MFMA, LDS A+B) ----------------
__global__ __launch_bounds__(256) void out_mfma(
    const u16* __restrict__ Mb, const u16* __restrict__ Wt,
    const float* __restrict__ bo, const float* __restrict__ H,
    float* __restrict__ out)
{
    __shared__ u16 As[64 * 256];
    __shared__ u16 Bs[2][128 * 68];

    const int tid = threadIdx.x;
    const int bx = blockIdx.x;     // 0..1
    const int by = blockIdx.y;     // 0..127
    const int row0 = by * 64;
    const u16* __restrict__ wb = Wt + (size_t)(768 + bx * 128) * 256;

    uint4 breg[4];
    #pragma unroll
    for (int i = 0; i < 4; ++i) {
        const int u = i * 256 + tid, col = u >> 3, seg = u & 7;
        breg[i] = *(const uint4*)&wb[col * 256 + seg * 8];
    }
    {
        const int r = tid >> 2, cb = (tid & 3) * 64;
        const u16* mp = Mb + (size_t)(row0 + r) * 256 + cb;
        const int swz = (r & 7) << 3;
        #pragma unroll
        for (int i = 0; i < 8; ++i) {
            uint4 v = *(const uint4*)(mp + i * 8);
            *(uint4*)(As + ((r * 256 + cb + i * 8) ^ swz)) = v;
        }
    }
    #pragma unroll
    for (int i = 0; i < 4; ++i) {
        const int u = i * 256 + tid, col = u >> 3, seg = u & 7;
        *(uint4*)&Bs[0][col * 68 + seg * 8] = breg[i];
    }
    __syncthreads();

    const int lane = tid & 63, w = tid >> 6;
    const int l15 = lane & 15, lhi = lane >> 4;
    const int rowa = w * 16 + l15;
    const int kb = lhi * 8;
    const int swa = (rowa & 7) << 3;

    bf16x8 af[8];
    #pragma unroll
    for (int ks = 0; ks < 8; ++ks)
        af[ks] = *(const bf16x8*)(As + ((rowa * 256 + ks * 32 + kb) ^ swa));

    f32x4 acc[8];
    #pragma unroll
    for (int i = 0; i < 8; ++i) acc[i] = (f32x4){0.f, 0.f, 0.f, 0.f};

    for (int s = 0; s < 4; ++s) {
        if (s < 3) {
            #pragma unroll
            for (int i = 0; i < 4; ++i) {
                const int u = i * 256 + tid, col = u >> 3, seg = u & 7;
                breg[i] = *(const uint4*)&wb[col * 256 + (s + 1) * 64 + seg * 8];
            }
        }
        #pragma unroll
        for (int ks2 = 0; ks2 < 2; ++ks2) {
            const int ks = s * 2 + ks2;
            #pragma unroll
            for (int i = 0; i < 8; ++i) {
                bf16x8 bf = *(const bf16x8*)&Bs[s & 1][(i * 16 + l15) * 68 + ks2 * 32 + kb];
                acc[i] = __builtin_amdgcn_mfma_f32_16x16x32_bf16(af[ks], bf, acc[i], 0, 0, 0);
            }
        }
        if (s < 3) {
            __syncthreads();
            #pragma unroll
            for (int i = 0; i < 4; ++i) {
                const int u = i * 256 + tid, col = u >> 3, seg = u & 7;
                *(uint4*)&Bs[(s + 1) & 1][col * 68 + seg * 8] = breg[i];
            }
            __syncthreads();
        }
    }

    #pragma unroll
    for (int i = 0; i < 8; ++i) {
        const int col = bx * 128 + i * 16 + l15;
        const float bi = bo[col];
        #pragma unroll
        for (int reg = 0; reg < 4; ++reg) {
            const int r = row0 + w * 16 + lhi * 4 + reg;
            const size_t off = (size_t)r * 256 + col;
            out[off] = H[off] + acc[i][reg] + bi;
        }
    }
}

extern "C" void kernel_launch(void* const* d_in, const int* in_sizes, int n_in,
                              void* d_out, int out_size, void* d_ws, size_t ws_size,
                              hipStream_t stream) {
    const float* H  = (const float*)d_in[0];
    const float* Wq = (const float*)d_in[1];
    const float* bq = (const float*)d_in[2];
    const float* Wk = (const float*)d_in[3];
    const float* bk = (const float*)d_in[4];
    const float* Wv = (const float*)d_in[5];
    const float* bv = (const float*)d_in[6];
    const float* Wo = (const float*)d_in[7];
    const float* bo = (const float*)d_in[8];
    float* out = (float*)d_out;

    u16* Wt = (u16*)d_ws;                          // 1024*256
    u16* Qb = Wt + 1024 * 256;                     // 8192*256
    u16* Kx = Qb + (size_t)NROWS * 256;            // 2*LXK*256
    u16* Vt = Kx + (size_t)2 * LXK * 256;          // 2*256*LXV
    u16* Mb = Vt + (size_t)2 * 256 * LXV;          // 8192*256

    prep<<<96, 256, 0, stream>>>(Wq, Wk, Wv, Wo, bk, bv, Wt, Kx, Vt);
    qkv_mfma<<<dim3(6, 128), 256, 0, stream>>>(H, Wt, bq, bk, bv, Qb, Kx, Vt);
    attn_mfma<<<512, 256, 0, stream>>>(Qb, Kx, Vt, Mb);
    out_mfma<<<dim3(2, 128), 256, 0, stream>>>(Mb, Wt, bo, H, out);
}

// Round 7
// 51.528 us; speedup vs baseline: 1.3187x; 1.1342x over previous
//
#include <hip/hip_runtime.h>
#include <hip/hip_bf16.h>

#define D 256
#define NROWS 8192
#define LXK 4160         // Kx rows per batch: 64 prefix + 4096
#define LXV 4176         // Vt col stride per batch: 64 prefix + 4096 + 16 tail pad
#define VPAD 64

#define QBLK 16          // attn rows per block
#define KKEYS 80         // staged keys per block
#define SSTR 84          // Sb row stride (f32)
#define PSTR 104         // Pb row stride (u16), cols 80..95 zeroed

typedef unsigned int u32;
typedef unsigned short u16;

typedef short bf16x8 __attribute__((ext_vector_type(8)));
typedef float f32x4 __attribute__((ext_vector_type(4)));

__device__ __forceinline__ u16 f2bf(float f) {
    u32 x = __float_as_uint(f);
    x += 0x7fffu + ((x >> 16) & 1u);
    return (u16)(x >> 16);
}
__device__ __forceinline__ u32 pk2(float a, float b) {
    return (u32)f2bf(a) | ((u32)f2bf(b) << 16);
}

// ---------------- Kernel 1: QKV projection (MFMA, in-kernel W transpose) ----------------
// 64 rows x 128 cols per block over [8192 x 768]. B built from raw fp32 W via
// register transpose: load rows k,k+1 -> pk2 -> ds_write_b32 into k-packed Bs.
__global__ __launch_bounds__(256) void qkv_mfma(
    const float* __restrict__ H,
    const float* __restrict__ Wq, const float* __restrict__ Wk,
    const float* __restrict__ Wv,
    const float* __restrict__ bq, const float* __restrict__ bkb,
    const float* __restrict__ bvb,
    u16* __restrict__ Qb, u16* __restrict__ Kx, u16* __restrict__ Vt)
{
    __shared__ u16 As[64 * 256];
    __shared__ u16 Bs[2][128 * 68];

    const int tid = threadIdx.x;
    const int bx = blockIdx.x;     // 0..5
    const int by = blockIdx.y;     // 0..127
    const int row0 = by * 64;
    const int mat = bx >> 1;       // 0=Q 1=K 2=V
    const int n0 = (bx & 1) * 128;
    const float* __restrict__ W = (mat == 0) ? Wq : (mat == 1) ? Wk : Wv;

    // transpose-stage mapping: thread covers k-pair kp (0..31) x 16 cols
    const int kp = tid >> 3, ng = tid & 7;

    float4 wa[4], wb4[4];
    {   // issue W slice-0 loads
        const float* wr0 = W + (size_t)(kp * 2) * 256 + n0 + ng * 16;
        #pragma unroll
        for (int j = 0; j < 4; ++j) {
            wa[j]  = *(const float4*)(wr0 + j * 4);
            wb4[j] = *(const float4*)(wr0 + 256 + j * 4);
        }
    }
    // stage A (fp32 -> bf16, XOR swizzle in 8-u16 units)
    {
        const int r = tid >> 2, cb = (tid & 3) * 64;
        const float* hp = H + (size_t)(row0 + r) * 256 + cb;
        const int swz = (r & 7) << 3;
        #pragma unroll
        for (int i = 0; i < 16; ++i) {
            float4 h4 = *(const float4*)(hp + i * 4);
            uint2 pv; pv.x = pk2(h4.x, h4.y); pv.y = pk2(h4.z, h4.w);
            *(uint2*)(As + ((r * 256 + cb + i * 4) ^ swz)) = pv;
        }
    }
    {   // pack+write W slice 0 into Bs[0] (k-packed [n][k])
        u32* bd = (u32*)&Bs[0][0];
        #pragma unroll
        for (int j = 0; j < 4; ++j)
            #pragma unroll
            for (int i = 0; i < 4; ++i)
                bd[(ng * 16 + j * 4 + i) * 34 + kp] = pk2(wa[j][i], wb4[j][i]);
    }
    __syncthreads();

    const int lane = tid & 63, w = tid >> 6;
    const int l15 = lane & 15, lhi = lane >> 4;
    const int rowa = w * 16 + l15;
    const int kb = lhi * 8;
    const int swa = (rowa & 7) << 3;

    bf16x8 af[8];
    #pragma unroll
    for (int ks = 0; ks < 8; ++ks)
        af[ks] = *(const bf16x8*)(As + ((rowa * 256 + ks * 32 + kb) ^ swa));

    f32x4 acc[8];
    #pragma unroll
    for (int i = 0; i < 8; ++i) acc[i] = (f32x4){0.f, 0.f, 0.f, 0.f};

    for (int s = 0; s < 4; ++s) {
        if (s < 3) {
            const float* wr0 = W + (size_t)((s + 1) * 64 + kp * 2) * 256 + n0 + ng * 16;
            #pragma unroll
            for (int j = 0; j < 4; ++j) {
                wa[j]  = *(const float4*)(wr0 + j * 4);
                wb4[j] = *(const float4*)(wr0 + 256 + j * 4);
            }
        }
        #pragma unroll
        for (int ks2 = 0; ks2 < 2; ++ks2) {
            const int ks = s * 2 + ks2;
            #pragma unroll
            for (int i = 0; i < 8; ++i) {
                bf16x8 bf = *(const bf16x8*)&Bs[s & 1][(i * 16 + l15) * 68 + ks2 * 32 + kb];
                acc[i] = __builtin_amdgcn_mfma_f32_16x16x32_bf16(af[ks], bf, acc[i], 0, 0, 0);
            }
        }
        if (s < 3) {
            __syncthreads();
            u32* bd = (u32*)&Bs[(s + 1) & 1][0];
            #pragma unroll
            for (int j = 0; j < 4; ++j)
                #pragma unroll
                for (int i = 0; i < 4; ++i)
                    bd[(ng * 16 + j * 4 + i) * 34 + kp] = pk2(wa[j][i], wb4[j][i]);
            __syncthreads();
        }
    }

    const int batch = row0 >> 12, lr0 = row0 & 4095;

    if (mat == 2) {
        // V: bounce through LDS (reuse As) for coalesced transposed stores.
        u16* Vtmp = As;   // [128][72]
        __syncthreads();
        #pragma unroll
        for (int i = 0; i < 8; ++i) {
            const int dl = i * 16 + l15;               // local dim 0..127
            const float bi = bvb[n0 + dl];
            #pragma unroll
            for (int reg = 0; reg < 4; ++reg) {
                const int key = w * 16 + lhi * 4 + reg;  // local key 0..63
                Vtmp[dl * 72 + key] = f2bf(acc[i][reg] + bi);
            }
        }
        __syncthreads();
        #pragma unroll
        for (int rep = 0; rep < 2; ++rep) {
            const int dl = rep * 64 + (tid >> 2), q = tid & 3;
            uint4 v0 = *(const uint4*)&Vtmp[dl * 72 + q * 16];
            uint4 v1 = *(const uint4*)&Vtmp[dl * 72 + q * 16 + 8];
            const int gd = n0 + dl;
            u16* dst = Vt + ((size_t)batch * 256 + gd) * LXV + VPAD + lr0 + q * 16;
            *(uint4*)dst = v0;
            *(uint4*)(dst + 8) = v1;
        }
    } else {
        // Q/K: bounce through LDS (reuse As) for coalesced row stores.
        u16* Tq = As;     // [64][136]
        const float* bias = (mat == 0) ? bq : bkb;
        __syncthreads();
        #pragma unroll
        for (int i = 0; i < 8; ++i) {
            const int cl = i * 16 + l15;
            const float bi = bias[n0 + cl];
            #pragma unroll
            for (int reg = 0; reg < 4; ++reg)
                Tq[(w * 16 + lhi * 4 + reg) * 136 + cl] = f2bf(acc[i][reg] + bi);
        }
        __syncthreads();
        {
            const int r = tid >> 2, c32 = (tid & 3) * 32;
            uint4 v0 = *(const uint4*)&Tq[r * 136 + c32];
            uint4 v1 = *(const uint4*)&Tq[r * 136 + c32 + 8];
            uint4 v2 = *(const uint4*)&Tq[r * 136 + c32 + 16];
            uint4 v3 = *(const uint4*)&Tq[r * 136 + c32 + 24];
            u16* dst;
            if (mat == 0) dst = Qb + (size_t)(row0 + r) * 256 + n0 + c32;
            else          dst = Kx + ((size_t)batch * LXK + VPAD + lr0 + r) * 256 + n0 + c32;
            *(uint4*)(dst + 0)  = v0;
            *(uint4*)(dst + 8)  = v1;
            *(uint4*)(dst + 16) = v2;
            *(uint4*)(dst + 24) = v3;
        }
    }

    // ---- virtual-prefix writes (designated blocks; consumers run next kernel) ----
    if (bx == 2 && (by & 63) == 0) {          // Kx prefix rows = bk
        const int batch2 = by >> 6;
        const int rowp = tid >> 2, c64 = (tid & 3) * 64;
        u16* dst = Kx + ((size_t)batch2 * LXK + rowp) * 256 + c64;
        #pragma unroll
        for (int j = 0; j < 8; ++j) {
            float4 a = *(const float4*)&bkb[c64 + j * 8];
            float4 b = *(const float4*)&bkb[c64 + j * 8 + 4];
            uint4 o;
            o.x = pk2(a.x, a.y); o.y = pk2(a.z, a.w);
            o.z = pk2(b.x, b.y); o.w = pk2(b.z, b.w);
            *(uint4*)(dst + j * 8) = o;
        }
    }
    if (bx == 4 && (by & 63) == 0) {          // Vt prefix cols = bv
        const int batch2 = by >> 6;
        const u16 val = f2bf(bvb[tid]);
        const u32 vv = (u32)val | ((u32)val << 16);
        uint4 o; o.x = vv; o.y = vv; o.z = vv; o.w = vv;
        u16* dst = Vt + ((size_t)batch2 * 256 + tid) * LXV;
        #pragma unroll
        for (int j = 0; j < 8; ++j) *(uint4*)(dst + j * 8) = o;
    }
}

// ---------------- Kernel 2: fused 3-window attention (MFMA) ----------------
// 16 rows/block, 256 threads, grid 512. K staged in LDS (swizzled); V^T from global.
__global__ __launch_bounds__(256) void attn_mfma(
    const u16* __restrict__ Qb, const u16* __restrict__ Kx,
    const u16* __restrict__ Vt, u16* __restrict__ Mb)
{
    __shared__ u16 Ks[KKEYS * 256];       // XOR-swizzled [key][feat]
    __shared__ float Sb[QBLK * SSTR];
    __shared__ u16 Pb[QBLK * PSTR];

    const int tid = threadIdx.x;
    const int lane = tid & 63, w = tid >> 6;   // w 0..3
    const int l15 = lane & 15, lhi = lane >> 4;
    const int r0 = blockIdx.x * QBLK;
    const int batch = r0 >> 12;
    const int lb0 = r0 & 4095;
    const size_t kbase = (size_t)batch * LXK + lb0;

    // ---- stage K (80 rows, swizzled) ----
    uint4 kreg[10];
    #pragma unroll
    for (int i = 0; i < 10; ++i) {
        const int u = i * 256 + tid;
        const int row = u >> 5, seg = u & 31;
        kreg[i] = *(const uint4*)&Kx[(kbase + row) * 256 + seg * 8];
    }
    #pragma unroll
    for (int i = 0; i < 10; ++i) {
        const int u = i * 256 + tid;
        const int row = u >> 5, seg = u & 31;
        *(uint4*)&Ks[row * 256 + (seg ^ (row & 7)) * 8] = kreg[i];
    }
    __syncthreads();

    // ---- QK^T: 5 keytiles over 4 waves (wave 0 also does tile 4) ----
    const float scale = 0.0625f;
    const u16* qp = Qb + (size_t)(r0 + l15) * 256;
    bf16x8 qf[8];
    #pragma unroll
    for (int ks = 0; ks < 8; ++ks) qf[ks] = *(const bf16x8*)(qp + ks * 32 + lhi * 8);
    for (int T = w; T < 5; T += 4) {
        const int key = T * 16 + l15;
        f32x4 acc = (f32x4){0.f, 0.f, 0.f, 0.f};
        #pragma unroll
        for (int ks = 0; ks < 8; ++ks) {
            bf16x8 kf = *(const bf16x8*)&Ks[key * 256 + ((ks * 4 + lhi) ^ (key & 7)) * 8];
            acc = __builtin_amdgcn_mfma_f32_16x16x32_bf16(qf[ks], kf, acc, 0, 0, 0);
        }
        #pragma unroll
        for (int reg = 0; reg < 4; ++reg)
            Sb[(lhi * 4 + reg) * SSTR + T * 16 + l15] = acc[reg] * scale;
    }
    __syncthreads();

    // ---- nested softmax: 16 rows x 16 lanes, 5 cols/lane ----
    {
        const int ri = w * 4 + lhi;
        const int jb = l15;
        float s5[5];
        float m = -1e30f;
        #pragma unroll
        for (int c = 0; c < 5; ++c) {
            const int j = jb + 16 * c;
            const float x = Sb[ri * SSTR + j];
            const bool v = (j >= ri + 1) && (j <= ri + 64);
            s5[c] = v ? x : -1e30f;
            m = fmaxf(m, s5[c]);
        }
        #pragma unroll
        for (int o = 1; o < 16; o <<= 1) m = fmaxf(m, __shfl_xor(m, o));
        float e5[5], z64 = 0.f, z16 = 0.f, z4 = 0.f;
        #pragma unroll
        for (int c = 0; c < 5; ++c) {
            const int j = jb + 16 * c;
            const float e = __expf(s5[c] - m);
            e5[c] = e;
            z64 += e;
            if (j >= ri + 49) z16 += e;
            if (j >= ri + 61) z4 += e;
        }
        #pragma unroll
        for (int o = 1; o < 16; o <<= 1) {
            z64 += __shfl_xor(z64, o);
            z16 += __shfl_xor(z16, o);
            z4  += __shfl_xor(z4, o);
        }
        const float i64 = 1.f / z64, i16 = 1.f / z16, i4 = 1.f / z4;
        #pragma unroll
        for (int c = 0; c < 5; ++c) {
            const int j = jb + 16 * c;
            float wt = e5[c] * (i64 + (j >= ri + 49 ? i16 : 0.f) + (j >= ri + 61 ? i4 : 0.f)) * (1.f / 3.f);
            Pb[ri * PSTR + j] = f2bf(wt);
        }
        Pb[ri * PSTR + 80 + jb] = 0;   // zero pad cols 80..95
    }
    __syncthreads();

    // ---- PV: M[16][256] = P[16][96] @ V^T[96][256]; V fragments from global ----
    bf16x8 pa[3];
    #pragma unroll
    for (int ks = 0; ks < 3; ++ks)
        pa[ks] = *(const bf16x8*)&Pb[l15 * PSTR + ks * 32 + lhi * 8];
    #pragma unroll
    for (int i = 0; i < 4; ++i) {
        const int dt = w * 4 + i;
        const u16* vrow = Vt + ((size_t)batch * 256 + dt * 16 + l15) * LXV + lb0;
        f32x4 acc = (f32x4){0.f, 0.f, 0.f, 0.f};
        #pragma unroll
        for (int ks = 0; ks < 3; ++ks) {
            bf16x8 vb = *(const bf16x8*)(vrow + ks * 32 + lhi * 8);
            acc = __builtin_amdgcn_mfma_f32_16x16x32_bf16(pa[ks], vb, acc, 0, 0, 0);
        }
        #pragma unroll
        for (int reg = 0; reg < 4; ++reg)
            Mb[(size_t)(r0 + lhi * 4 + reg) * 256 + dt * 16 + l15] = f2bf(acc[reg]);
    }
}

// ---------------- Kernel 3: output projection + residual (in-kernel Wo transpose) ----------------
__global__ __launch_bounds__(256) void out_mfma(
    const u16* __restrict__ Mb, const float* __restrict__ Wo,
    const float* __restrict__ bo, const float* __restrict__ H,
    float* __restrict__ out)
{
    __shared__ u16 As[64 * 256];
    __shared__ u16 Bs[2][128 * 68];

    const int tid = threadIdx.x;
    const int bx = blockIdx.x;     // 0..1
    const int by = blockIdx.y;     // 0..127
    const int row0 = by * 64;
    const int n0 = bx * 128;
    const int kp = tid >> 3, ng = tid & 7;

    float4 wa[4], wb4[4];
    {
        const float* wr0 = Wo + (size_t)(kp * 2) * 256 + n0 + ng * 16;
        #pragma unroll
        for (int j = 0; j < 4; ++j) {
            wa[j]  = *(const float4*)(wr0 + j * 4);
            wb4[j] = *(const float4*)(wr0 + 256 + j * 4);
        }
    }
    {
        const int r = tid >> 2, cb = (tid & 3) * 64;
        const u16* mp = Mb + (size_t)(row0 + r) * 256 + cb;
        const int swz = (r & 7) << 3;
        #pragma unroll
        for (int i = 0; i < 8; ++i) {
            uint4 v = *(const uint4*)(mp + i * 8);
            *(uint4*)(As + ((r * 256 + cb + i * 8) ^ swz)) = v;
        }
    }
    {
        u32* bd = (u32*)&Bs[0][0];
        #pragma unroll
        for (int j = 0; j < 4; ++j)
            #pragma unroll
            for (int i = 0; i < 4; ++i)
                bd[(ng * 16 + j * 4 + i) * 34 + kp] = pk2(wa[j][i], wb4[j][i]);
    }
    __syncthreads();

    const int lane = tid & 63, w = tid >> 6;
    const int l15 = lane & 15, lhi = lane >> 4;
    const int rowa = w * 16 + l15;
    const int kb = lhi * 8;
    const int swa = (rowa & 7) << 3;

    bf16x8 af[8];
    #pragma unroll
    for (int ks = 0; ks < 8; ++ks)
        af[ks] = *(const bf16x8*)(As + ((rowa * 256 + ks * 32 + kb) ^ swa));

    f32x4 acc[8];
    #pragma unroll
    for (int i = 0; i < 8; ++i) acc[i] = (f32x4){0.f, 0.f, 0.f, 0.f};

    for (int s = 0; s < 4; ++s) {
        if (s < 3) {
            const float* wr0 = Wo + (size_t)((s + 1) * 64 + kp * 2) * 256 + n0 + ng * 16;
            #pragma unroll
            for (int j = 0; j < 4; ++j) {
                wa[j]  = *(const float4*)(wr0 + j * 4);
                wb4[j] = *(const float4*)(wr0 + 256 + j * 4);
            }
        }
        #pragma unroll
        for (int ks2 = 0; ks2 < 2; ++ks2) {
            const int ks = s * 2 + ks2;
            #pragma unroll
            for (int i = 0; i < 8; ++i) {
                bf16x8 bf = *(const bf16x8*)&Bs[s & 1][(i * 16 + l15) * 68 + ks2 * 32 + kb];
                acc[i] = __builtin_amdgcn_mfma_f32_16x16x32_bf16(af[ks], bf, acc[i], 0, 0, 0);
            }
        }
        if (s < 3) {
            __syncthreads();
            u32* bd = (u32*)&Bs[(s + 1) & 1][0];
            #pragma unroll
            for (int j = 0; j < 4; ++j)
                #pragma unroll
                for (int i = 0; i < 4; ++i)
                    bd[(ng * 16 + j * 4 + i) * 34 + kp] = pk2(wa[j][i], wb4[j][i]);
            __syncthreads();
        }
    }

    #pragma unroll
    for (int i = 0; i < 8; ++i) {
        const int col = n0 + i * 16 + l15;
        const float bi = bo[col];
        #pragma unroll
        for (int reg = 0; reg < 4; ++reg) {
            const int r = row0 + w * 16 + lhi * 4 + reg;
            const size_t off = (size_t)r * 256 + col;
            out[off] = H[off] + acc[i][reg] + bi;
        }
    }
}

extern "C" void kernel_launch(void* const* d_in, const int* in_sizes, int n_in,
                              void* d_out, int out_size, void* d_ws, size_t ws_size,
                              hipStream_t stream) {
    const float* H  = (const float*)d_in[0];
    const float* Wq = (const float*)d_in[1];
    const float* bq = (const float*)d_in[2];
    const float* Wk = (const float*)d_in[3];
    const float* bk = (const float*)d_in[4];
    const float* Wv = (const float*)d_in[5];
    const float* bv = (const float*)d_in[6];
    const float* Wo = (const float*)d_in[7];
    const float* bo = (const float*)d_in[8];
    float* out = (float*)d_out;

    u16* Qb = (u16*)d_ws;                          // 8192*256
    u16* Kx = Qb + (size_t)NROWS * 256;            // 2*LXK*256
    u16* Vt = Kx + (size_t)2 * LXK * 256;          // 2*256*LXV
    u16* Mb = Vt + (size_t)2 * 256 * LXV;          // 8192*256

    qkv_mfma<<<dim3(6, 128), 256, 0, stream>>>(H, Wq, Wk, Wv, bq, bk, bv, Qb, Kx, Vt);
    attn_mfma<<<512, 256, 0, stream>>>(Qb, Kx, Vt, Mb);
    out_mfma<<<dim3(2, 128), 256, 0, stream>>>(Mb, Wo, bo, H, out);
}